// Round 12
// baseline (218.882 us; speedup 1.0000x reference)
//
#include <hip/hip_runtime.h>
#include <stdint.h>

typedef uint32_t u32;
typedef unsigned long long u64;
using bf16x8 = __attribute__((ext_vector_type(8))) short;
using f32x4  = __attribute__((ext_vector_type(4))) float;

#define MFMA16(a, b, c) __builtin_amdgcn_mfma_f32_16x16x32_bf16((a), (b), (c), 0, 0, 0)

__device__ __forceinline__ unsigned short f2bf(float f) {
  u32 u = __builtin_bit_cast(u32, f);
  return (unsigned short)((u + 0x7FFFu + ((u >> 16) & 1u)) >> 16);  // RNE
}

__device__ __forceinline__ void gl_lds16(const unsigned short* g, unsigned short* l) {
  __builtin_amdgcn_global_load_lds((const __attribute__((address_space(1))) void*)g,
                                   (__attribute__((address_space(3))) void*)l, 16, 0, 0);
}

// pack 2 fp32 -> 2 bf16 (RNE) in one instr
__device__ __forceinline__ u32 cvtpk(float a, float b) {
  u32 r;
  asm("v_cvt_pk_bf16_f32 %0, %1, %2" : "=v"(r) : "v"(a), "v"(b));
  return r;
}

// ---------------- Threefry-2x32-20, key = (0, 42), single-instr rotates ----------------
__device__ __forceinline__ u32 rotl(u32 x, int r) {
  return __builtin_amdgcn_alignbit(x, x, 32 - r);
}
#define TFR(r) x0 += x1; x1 = rotl(x1, r) ^ x0;

// partitionable-threefry word for flat index j: counter (0, j), word = o0 ^ o1.
// keep (mask=False) <=> MSB == 1.
__device__ __forceinline__ u32 tf_word(u32 j) {
  const u32 ks1 = 42u, ks2 = 0x1BD11BDAu ^ 42u;
  u32 x0 = 0u;        // i0 = 0, ks0 = 0
  u32 x1 = j + ks1;
  TFR(13) TFR(15) TFR(26) TFR(6)
  x0 += ks1; x1 += ks2 + 1u;
  TFR(17) TFR(29) TFR(16) TFR(24)
  x0 += ks2; x1 += 2u;
  TFR(13) TFR(15) TFR(26) TFR(6)
  x1 += ks1 + 3u;
  TFR(17) TFR(29) TFR(16) TFR(24)
  x0 += ks1; x1 += ks2 + 4u;
  TFR(13) TFR(15) TFR(26) TFR(6)
  x0 += ks2; x1 += 5u;
  return x0 ^ x1;
}

// ---------------- bf16 GEMM (m97 structure), C = A[M,512] * Bm[N,512]^T ----------
// r12: cvt_kernel eliminated. EPI 0: A = x (fp32, reg-staged cvt_pk), B = qkv_w (fp32,
// reg-staged); epilogue +bias, Q pre-scaled 0.125*log2e, scatter Q/K/VT bf16.
// EPI 1: A = attn_out (bf16 via global_load_lds), B = proj_w (fp32, reg-staged);
// epilogue +bias, fp32 store.
template<int EPI>
__global__ __launch_bounds__(256)
void gemm_kernel(const void* Ap, const float* B32, const float* __restrict__ bias,
                 unsigned short* __restrict__ q_out, unsigned short* __restrict__ k_out,
                 unsigned short* __restrict__ vt_out, float* __restrict__ f_out) {
  __shared__ __align__(16) unsigned short lA[128 * 32];
  __shared__ __align__(16) unsigned short lB[128 * 32];
  const int tid = threadIdx.x;
  const int lane = tid & 63, w = tid >> 6;
  const int hi = lane >> 4, lo = lane & 15;
  const int wm = w >> 1, wn = w & 1;
  const int m0 = blockIdx.y * 128, n0 = blockIdx.x * 128;
  const int srow = lane >> 2, skc = (lane & 3) * 8;

  f32x4 acc[4][4];
#pragma unroll
  for (int i = 0; i < 4; ++i)
#pragma unroll
    for (int j = 0; j < 4; ++j) acc[i][j] = (f32x4){0.f, 0.f, 0.f, 0.f};

  for (int kt = 0; kt < 16; ++kt) {
    const int k0 = kt * 32;
    __syncthreads();  // previous compute done before overwrite
#pragma unroll
    for (int c = 0; c < 2; ++c) {
      const int rr = (w * 2 + c) * 16 + srow;
      const int loff = (w * 2 + c) * 512 + srow * 32 + skc;  // shorts
      if (EPI == 0) {
        const float* ga = (const float*)Ap + (size_t)(m0 + rr) * 512 + k0 + skc;
        float4 a0 = *(const float4*)ga, a1 = *(const float4*)(ga + 4);
        uint4 pa = {cvtpk(a0.x, a0.y), cvtpk(a0.z, a0.w), cvtpk(a1.x, a1.y), cvtpk(a1.z, a1.w)};
        *reinterpret_cast<uint4*>(&lA[loff]) = pa;
      } else {
        gl_lds16((const unsigned short*)Ap + (size_t)(m0 + rr) * 512 + k0 + skc,
                 &lA[(w * 2 + c) * 512]);
      }
      const float* gb = B32 + (size_t)(n0 + rr) * 512 + k0 + skc;
      float4 b0 = *(const float4*)gb, b1 = *(const float4*)(gb + 4);
      uint4 pb = {cvtpk(b0.x, b0.y), cvtpk(b0.z, b0.w), cvtpk(b1.x, b1.y), cvtpk(b1.z, b1.w)};
      *reinterpret_cast<uint4*>(&lB[loff]) = pb;
    }
    __syncthreads();  // compiler drains vmcnt (gl_lds) + lgkmcnt (ds_write) before barrier

    bf16x8 af[4], bfr[4];
#pragma unroll
    for (int i = 0; i < 4; ++i) af[i]  = *(const bf16x8*)&lA[(wm * 64 + i * 16 + lo) * 32 + hi * 8];
#pragma unroll
    for (int i = 0; i < 4; ++i) bfr[i] = *(const bf16x8*)&lB[(wn * 64 + i * 16 + lo) * 32 + hi * 8];
#pragma unroll
    for (int i = 0; i < 4; ++i)
#pragma unroll
      for (int j = 0; j < 4; ++j)
        acc[i][j] = MFMA16(af[i], bfr[j], acc[i][j]);
  }

  // C/D layout: col = lane&15, row = (lane>>4)*4 + reg  (m89/m91)
#pragma unroll
  for (int i = 0; i < 4; ++i) {
    const int rowb = m0 + wm * 64 + i * 16 + hi * 4;
#pragma unroll
    for (int j = 0; j < 4; ++j) {
      const int col = n0 + wn * 64 + j * 16 + lo;
      const float bv = bias[col];
      if (EPI == 0) {
        const int which = col >> 9, hh = (col >> 6) & 7, dd = col & 63;
        // Q: fold softmax SCALE (0.125) AND log2(e) so attn uses raw v_exp_f32.
        const float scl = (which == 0) ? 0.18033688011112042f : 1.0f;
#pragma unroll
        for (int r = 0; r < 4; ++r) {
          const int tok = rowb + r;
          const int b = tok >> 10, nt = tok & 1023;
          const int bh = b * 8 + hh;
          const unsigned short val = f2bf((acc[i][j][r] + bv) * scl);
          if (which == 0)      q_out[((size_t)((bh << 10) + nt)) * 64 + dd] = val;
          else if (which == 1) k_out[((size_t)((bh << 10) + nt)) * 64 + dd] = val;
          else                 vt_out[((size_t)bh * 64 + dd) * 1024 + nt] = val;
        }
      } else {
#pragma unroll
        for (int r = 0; r < 4; ++r)
          f_out[(size_t)(rowb + r) * 512 + col] = acc[i][j][r] + bv;
      }
    }
  }
}

// ---------------- fused attention + threefry mask, split-K x2, XCD-swizzled ----------------
// Grid 2048; xcd = bid&7, slot = bid>>3; bh = xcd*8 + slot/32 -> K/V L2-resident per XCD
// (r10: FETCH 104->27 MB). Block = 4 waves = 2 pairs; pair p owns 16 q-rows; wave half
// does keys half*512..+511; partials combine by fp32 add in LDS (no max tracking, r6).
// Swapped QK^T (A=K, B=Q): lane holds 4 consecutive keys of one q-row -> cvt_pk pairs +
// ds_write_b64. r12: raw v_exp_f32 (exp2f's OCML wrapper was multi-op) and VCC-free
// masking via ashr/and (keep <=> MSB -> all-ones mask; masked -> +0.0f).
__global__ __launch_bounds__(256, 8) void attn_kernel(
    const unsigned short* __restrict__ Qb, const unsigned short* __restrict__ Kb,
    const unsigned short* __restrict__ VTb, unsigned short* __restrict__ aout) {
  __shared__ __align__(16) unsigned short plds[4][1088];  // per-wave P tile, 136B row stride
  const int tid = threadIdx.x;
  const int lane = tid & 63, w = tid >> 6;
  const int hi = lane >> 4, lo = lane & 15;
  const int p = w & 1, half = w >> 1;
  const int bid = blockIdx.x;
  const int xcd = bid & 7, slot = bid >> 3;
  const int bh = (xcd << 3) | (slot >> 5);   // 8 bh per XCD
  const int qg = slot & 31;
  const int qs = qg * 32 + p * 16;

  bf16x8 qf[2];
#pragma unroll
  for (int dh = 0; dh < 2; ++dh)
    qf[dh] = *(const bf16x8*)&Qb[((size_t)(bh << 10) + qs + lo) * 64 + dh * 32 + hi * 8];

  f32x4 acc[4];
  f32x4 sacc = (f32x4){0.f, 0.f, 0.f, 0.f};
#pragma unroll
  for (int dt = 0; dt < 4; ++dt) acc[dt] = (f32x4){0.f, 0.f, 0.f, 0.f};
  bf16x8 ones;
#pragma unroll
  for (int j = 0; j < 8; ++j) ones[j] = (short)0x3F80;  // bf16 1.0

  // swapped layout: lane's q-row = qs+lo; lane's keys = k0 + t*16 + hi*4 + r
  const u32 jbase = ((u32)bh << 20) | ((u32)(qs + lo) << 10) | (u32)(hi * 4);
  const int ktbase = half * 8;
  unsigned short* mp = &plds[w][0];

  for (int i = 0; i < 8; ++i) {
    const int k0 = (ktbase + i) * 64;

#pragma unroll
    for (int t = 0; t < 4; ++t) {
      // S'^T tile t: A=K rows=keys, B=Q cols=qrows (Q pre-scaled by 0.125*log2e).
      // D: row hi*4+r = key (k0+t*16+hi*4+r), col lo = q-row.
      const unsigned short* kbp = &Kb[((size_t)(bh << 10) + k0 + t * 16 + lo) * 64 + hi * 8];
      f32x4 z = (f32x4){0.f, 0.f, 0.f, 0.f};
      z = MFMA16(*(const bf16x8*)kbp, qf[0], z);
      z = MFMA16(*(const bf16x8*)(kbp + 32), qf[1], z);

      // P = keep ? exp2(z) : 0, branch/VCC-free: exp bits AND sign-extended keep bit
      float pv[4];
#pragma unroll
      for (int r = 0; r < 4; ++r) {
        const u32 tf = tf_word(jbase + (u32)(k0 + t * 16 + r));
        float e;
        asm("v_exp_f32 %0, %1" : "=v"(e) : "v"(z[r]));      // raw 1-instr exp2
        const u32 eb = __builtin_bit_cast(u32, e) & (u32)((int)tf >> 31);
        pv[r] = __builtin_bit_cast(float, eb);               // masked -> +0.0f
      }
      const u32 u0 = cvtpk(pv[0], pv[1]);
      const u32 u1 = cvtpk(pv[2], pv[3]);
      // P[qrow=lo][key] at short offset lo*68 + key; keys t*16+hi*4..+3 contiguous, 8B-aligned
      *reinterpret_cast<u64*>(&mp[lo * 68 + t * 16 + hi * 4]) = ((u64)u1 << 32) | (u64)u0;
    }

    // compiler inserts the lgkmcnt for the same-base ds_write -> ds_read dependence
    bf16x8 pf[2];
#pragma unroll
    for (int ks = 0; ks < 2; ++ks)
      pf[ks] = *(const bf16x8*)&mp[lo * 68 + ks * 32 + hi * 8];  // A-frag: qrow lo, k=key
    sacc = MFMA16(pf[0], ones, sacc);   // row-sums ride the MFMA pipe
    sacc = MFMA16(pf[1], ones, sacc);
#pragma unroll
    for (int dt = 0; dt < 4; ++dt) {
      const unsigned short* vbp = &VTb[((size_t)(bh * 64 + dt * 16 + lo)) * 1024 + k0 + hi * 8];
      acc[dt] = MFMA16(pf[0], *(const bf16x8*)vbp, acc[dt]);
      acc[dt] = MFMA16(pf[1], *(const bf16x8*)(vbp + 32), acc[dt]);
    }
  }

  // ---- combine the two K-halves of each pair via LDS (reuses plds; 2x1040 fp32 <= 2176) ----
  float* fb = ((float*)&plds[0][0]) + p * 1040;
  __syncthreads();                       // all waves done with their P tiles
  if (half == 1) {                       // donor: keys 512..1023 partials
#pragma unroll
    for (int dt = 0; dt < 4; ++dt)
#pragma unroll
      for (int r = 0; r < 4; ++r)
        fb[(hi * 4 + r) * 64 + dt * 16 + lo] = acc[dt][r];
    if (lo == 0)
#pragma unroll
      for (int r = 0; r < 4; ++r) fb[1024 + hi * 4 + r] = sacc[r];
  }
  __syncthreads();
  if (half == 0) {                       // receiver: add, normalize, store
    const int b = bh >> 3, h = bh & 7;
#pragma unroll
    for (int r = 0; r < 4; ++r) {
      const float zt = sacc[r] + fb[1024 + hi * 4 + r];
      const float inv = 1.0f / zt;
      const int tok = (b << 10) + qs + hi * 4 + r;
#pragma unroll
      for (int dt = 0; dt < 4; ++dt) {
        const float av = acc[dt][r] + fb[(hi * 4 + r) * 64 + dt * 16 + lo];
        aout[(size_t)tok * 512 + h * 64 + dt * 16 + lo] = f2bf(av * inv);
      }
    }
  }
}

extern "C" void kernel_launch(void* const* d_in, const int* in_sizes, int n_in,
                              void* d_out, int out_size, void* d_ws, size_t ws_size,
                              hipStream_t stream) {
  const float* x      = (const float*)d_in[0];
  const float* qkv_w  = (const float*)d_in[1];
  const float* qkv_b  = (const float*)d_in[2];
  const float* proj_w = (const float*)d_in[3];
  const float* proj_b = (const float*)d_in[4];
  float* out = (float*)d_out;
  char* ws = (char*)d_ws;

  unsigned short* Qb  = (unsigned short*)(ws);             // 8,388,608 [bh][n][d], pre-scaled
  unsigned short* Kb  = (unsigned short*)(ws +  8388608);  // 8,388,608 [bh][n][d]
  unsigned short* VTb = (unsigned short*)(ws + 16777216);  // 8,388,608 [bh][d][n]
  unsigned short* ao  = (unsigned short*)(ws + 25165824);  // 8,388,608 attn_out bf16 [tok][512]
  // total 33.6 MB; ws_size proven >= 50.3 MB (round-3 sentinel)

  gemm_kernel<0><<<dim3(12, 64), 256, 0, stream>>>(x, qkv_w, qkv_b, Qb, Kb, VTb, nullptr);
  attn_kernel<<<2048, 256, 0, stream>>>(Qb, Kb, VTb, ao);
  gemm_kernel<1><<<dim3(4, 64), 256, 0, stream>>>(ao, proj_w, proj_b, nullptr, nullptr, nullptr, out);
}

// Round 13
// 201.445 us; speedup vs baseline: 1.0866x; 1.0866x over previous
//
#include <hip/hip_runtime.h>
#include <stdint.h>

typedef uint32_t u32;
typedef unsigned long long u64;
using bf16x8 = __attribute__((ext_vector_type(8))) short;
using f32x4  = __attribute__((ext_vector_type(4))) float;

#define MFMA16(a, b, c) __builtin_amdgcn_mfma_f32_16x16x32_bf16((a), (b), (c), 0, 0, 0)

__device__ __forceinline__ unsigned short f2bf(float f) {
  u32 u = __builtin_bit_cast(u32, f);
  return (unsigned short)((u + 0x7FFFu + ((u >> 16) & 1u)) >> 16);  // RNE
}

__device__ __forceinline__ void gl_lds16(const unsigned short* g, unsigned short* l) {
  __builtin_amdgcn_global_load_lds((const __attribute__((address_space(1))) void*)g,
                                   (__attribute__((address_space(3))) void*)l, 16, 0, 0);
}

// pack 2 fp32 -> 2 bf16 (RNE) in one instr
__device__ __forceinline__ u32 cvtpk(float a, float b) {
  u32 r;
  asm("v_cvt_pk_bf16_f32 %0, %1, %2" : "=v"(r) : "v"(a), "v"(b));
  return r;
}

// ---------------- Threefry-2x32-20, key = (0, 42), single-instr rotates ----------------
__device__ __forceinline__ u32 rotl(u32 x, int r) {
  return __builtin_amdgcn_alignbit(x, x, 32 - r);
}
#define TFR(r) x0 += x1; x1 = rotl(x1, r) ^ x0;

// partitionable-threefry word for flat index j: counter (0, j), word = o0 ^ o1.
// keep (mask=False) <=> MSB == 1.
__device__ __forceinline__ u32 tf_word(u32 j) {
  const u32 ks1 = 42u, ks2 = 0x1BD11BDAu ^ 42u;
  u32 x0 = 0u;        // i0 = 0, ks0 = 0
  u32 x1 = j + ks1;
  TFR(13) TFR(15) TFR(26) TFR(6)
  x0 += ks1; x1 += ks2 + 1u;
  TFR(17) TFR(29) TFR(16) TFR(24)
  x0 += ks2; x1 += 2u;
  TFR(13) TFR(15) TFR(26) TFR(6)
  x1 += ks1 + 3u;
  TFR(17) TFR(29) TFR(16) TFR(24)
  x0 += ks1; x1 += ks2 + 4u;
  TFR(13) TFR(15) TFR(26) TFR(6)
  x0 += ks2; x1 += 5u;
  return x0 ^ x1;
}

// ---------------- fp32 -> bf16 conversion of x, qkv_w, proj_w ----------------
// One-shot cvt pays for itself: GEMMs re-read A 12x / B 64x per pass; bf16 halves
// that traffic and enables global_load_lds staging (r12 lesson: removing this cost +21us).
__global__ __launch_bounds__(256) void cvt_kernel(
    const float* __restrict__ x, const float* __restrict__ qw, const float* __restrict__ pw,
    unsigned short* __restrict__ xb, unsigned short* __restrict__ qwb,
    unsigned short* __restrict__ pwb) {
  int t = blockIdx.x * 256 + threadIdx.x;
  const float4* src; unsigned short* dst; int idx;
  if (t < 1048576)      { src = (const float4*)x;  dst = xb;  idx = t; }
  else if (t < 1245184) { src = (const float4*)qw; dst = qwb; idx = t - 1048576; }
  else                  { src = (const float4*)pw; dst = pwb; idx = t - 1245184; }
  float4 v = src[idx];
  ushort4 o = make_ushort4(f2bf(v.x), f2bf(v.y), f2bf(v.z), f2bf(v.w));
  ((ushort4*)dst)[idx] = o;
}

// ---------------- bf16 GEMM (m97 structure), C = A[M,512] * Bm[N,512]^T ----------
// EPI 0: qkv epilogue (+bias; Q pre-scaled by 0.125*log2(e) so attn uses raw v_exp; scatter)
// EPI 1: proj epilogue (+bias, fp32 store)
template<int EPI>
__global__ __launch_bounds__(256)
void gemm_kernel(const unsigned short* __restrict__ A, const unsigned short* __restrict__ Bm,
                 const float* __restrict__ bias, unsigned short* __restrict__ q_out,
                 unsigned short* __restrict__ k_out, unsigned short* __restrict__ vt_out,
                 float* __restrict__ f_out) {
  __shared__ __align__(16) unsigned short lA[128 * 32];
  __shared__ __align__(16) unsigned short lB[128 * 32];
  const int tid = threadIdx.x;
  const int lane = tid & 63, w = tid >> 6;
  const int hi = lane >> 4, lo = lane & 15;
  const int wm = w >> 1, wn = w & 1;
  const int m0 = blockIdx.y * 128, n0 = blockIdx.x * 128;
  const int srow = lane >> 2, skc = (lane & 3) * 8;

  f32x4 acc[4][4];
#pragma unroll
  for (int i = 0; i < 4; ++i)
#pragma unroll
    for (int j = 0; j < 4; ++j) acc[i][j] = (f32x4){0.f, 0.f, 0.f, 0.f};

  for (int kt = 0; kt < 16; ++kt) {
    const int k0 = kt * 32;
    __syncthreads();
#pragma unroll
    for (int c = 0; c < 2; ++c) {
      const int rr = (w * 2 + c) * 16 + srow;
      gl_lds16(A  + (size_t)(m0 + rr) * 512 + k0 + skc, &lA[(w * 2 + c) * 512]);
      gl_lds16(Bm + (size_t)(n0 + rr) * 512 + k0 + skc, &lB[(w * 2 + c) * 512]);
    }
    __syncthreads();

    bf16x8 af[4], bfr[4];
#pragma unroll
    for (int i = 0; i < 4; ++i) af[i]  = *(const bf16x8*)&lA[(wm * 64 + i * 16 + lo) * 32 + hi * 8];
#pragma unroll
    for (int i = 0; i < 4; ++i) bfr[i] = *(const bf16x8*)&lB[(wn * 64 + i * 16 + lo) * 32 + hi * 8];
#pragma unroll
    for (int i = 0; i < 4; ++i)
#pragma unroll
      for (int j = 0; j < 4; ++j)
        acc[i][j] = MFMA16(af[i], bfr[j], acc[i][j]);
  }

  // C/D layout: col = lane&15, row = (lane>>4)*4 + reg  (m89/m91)
#pragma unroll
  for (int i = 0; i < 4; ++i) {
    const int rowb = m0 + wm * 64 + i * 16 + hi * 4;
#pragma unroll
    for (int j = 0; j < 4; ++j) {
      const int col = n0 + wn * 64 + j * 16 + lo;
      const float bv = bias[col];
      if (EPI == 0) {
        const int which = col >> 9, hh = (col >> 6) & 7, dd = col & 63;
        // Q: fold softmax SCALE (0.125) AND log2(e) so attn uses raw v_exp_f32.
        const float scl = (which == 0) ? 0.18033688011112042f : 1.0f;
#pragma unroll
        for (int r = 0; r < 4; ++r) {
          const int tok = rowb + r;
          const int b = tok >> 10, nt = tok & 1023;
          const int bh = b * 8 + hh;
          const unsigned short val = f2bf((acc[i][j][r] + bv) * scl);
          if (which == 0)      q_out[((size_t)((bh << 10) + nt)) * 64 + dd] = val;
          else if (which == 1) k_out[((size_t)((bh << 10) + nt)) * 64 + dd] = val;
          else                 vt_out[((size_t)bh * 64 + dd) * 1024 + nt] = val;
        }
      } else {
#pragma unroll
        for (int r = 0; r < 4; ++r)
          f_out[(size_t)(rowb + r) * 512 + col] = acc[i][j][r] + bv;
      }
    }
  }
}

// ---------------- fused attention + threefry mask, split-K x2, XCD-swizzled ----------------
// Grid 2048; xcd = bid&7, slot = bid>>3; bh = xcd*8 + slot/32 -> K/V L2-resident per XCD
// (r10: FETCH 104->27 MB). Block = 4 waves = 2 pairs; pair p owns 16 q-rows; wave half
// does keys half*512..+511; partials combine by fp32 add in LDS (no max tracking, r6).
// Swapped QK^T (A=K, B=Q): lane holds 4 consecutive keys of one q-row -> cvt_pk pairs +
// ds_write_b64; raw v_exp_f32; VCC-free masking (ashr/and). r13: setprio(1) around the
// PV MFMA cluster (T5 regime: threefry-phase and MFMA-phase waves co-resident).
__global__ __launch_bounds__(256, 8) void attn_kernel(
    const unsigned short* __restrict__ Qb, const unsigned short* __restrict__ Kb,
    const unsigned short* __restrict__ VTb, unsigned short* __restrict__ aout) {
  __shared__ __align__(16) unsigned short plds[4][1088];  // per-wave P tile, 136B row stride
  const int tid = threadIdx.x;
  const int lane = tid & 63, w = tid >> 6;
  const int hi = lane >> 4, lo = lane & 15;
  const int p = w & 1, half = w >> 1;
  const int bid = blockIdx.x;
  const int xcd = bid & 7, slot = bid >> 3;
  const int bh = (xcd << 3) | (slot >> 5);   // 8 bh per XCD
  const int qg = slot & 31;
  const int qs = qg * 32 + p * 16;

  bf16x8 qf[2];
#pragma unroll
  for (int dh = 0; dh < 2; ++dh)
    qf[dh] = *(const bf16x8*)&Qb[((size_t)(bh << 10) + qs + lo) * 64 + dh * 32 + hi * 8];

  f32x4 acc[4];
  f32x4 sacc = (f32x4){0.f, 0.f, 0.f, 0.f};
#pragma unroll
  for (int dt = 0; dt < 4; ++dt) acc[dt] = (f32x4){0.f, 0.f, 0.f, 0.f};
  bf16x8 ones;
#pragma unroll
  for (int j = 0; j < 8; ++j) ones[j] = (short)0x3F80;  // bf16 1.0

  // swapped layout: lane's q-row = qs+lo; lane's keys = k0 + t*16 + hi*4 + r
  const u32 jbase = ((u32)bh << 20) | ((u32)(qs + lo) << 10) | (u32)(hi * 4);
  const int ktbase = half * 8;
  unsigned short* mp = &plds[w][0];

  for (int i = 0; i < 8; ++i) {
    const int k0 = (ktbase + i) * 64;

#pragma unroll
    for (int t = 0; t < 4; ++t) {
      // S'^T tile t: A=K rows=keys, B=Q cols=qrows (Q pre-scaled by 0.125*log2e).
      // D: row hi*4+r = key (k0+t*16+hi*4+r), col lo = q-row.
      const unsigned short* kbp = &Kb[((size_t)(bh << 10) + k0 + t * 16 + lo) * 64 + hi * 8];
      f32x4 z = (f32x4){0.f, 0.f, 0.f, 0.f};
      z = MFMA16(*(const bf16x8*)kbp, qf[0], z);
      z = MFMA16(*(const bf16x8*)(kbp + 32), qf[1], z);

      // P = keep ? exp2(z) : 0, branch/VCC-free: exp bits AND sign-extended keep bit
      float pv[4];
#pragma unroll
      for (int r = 0; r < 4; ++r) {
        const u32 tf = tf_word(jbase + (u32)(k0 + t * 16 + r));
        float e;
        asm("v_exp_f32 %0, %1" : "=v"(e) : "v"(z[r]));      // raw 1-instr exp2
        const u32 eb = __builtin_bit_cast(u32, e) & (u32)((int)tf >> 31);
        pv[r] = __builtin_bit_cast(float, eb);               // masked -> +0.0f
      }
      const u32 u0 = cvtpk(pv[0], pv[1]);
      const u32 u1 = cvtpk(pv[2], pv[3]);
      // P[qrow=lo][key] at short offset lo*68 + key; keys t*16+hi*4..+3 contiguous, 8B-aligned
      *reinterpret_cast<u64*>(&mp[lo * 68 + t * 16 + hi * 4]) = ((u64)u1 << 32) | (u64)u0;
    }

    // compiler/HW order the same-base ds_write -> ds_read dependence (per-wave in-order DS)
    bf16x8 pf[2];
#pragma unroll
    for (int ks = 0; ks < 2; ++ks)
      pf[ks] = *(const bf16x8*)&mp[lo * 68 + ks * 32 + hi * 8];  // A-frag: qrow lo, k=key
    __builtin_amdgcn_s_setprio(1);       // favor MFMA-phase wave on the CU scheduler (T5)
    sacc = MFMA16(pf[0], ones, sacc);    // row-sums ride the MFMA pipe
    sacc = MFMA16(pf[1], ones, sacc);
#pragma unroll
    for (int dt = 0; dt < 4; ++dt) {
      const unsigned short* vbp = &VTb[((size_t)(bh * 64 + dt * 16 + lo)) * 1024 + k0 + hi * 8];
      acc[dt] = MFMA16(pf[0], *(const bf16x8*)vbp, acc[dt]);
      acc[dt] = MFMA16(pf[1], *(const bf16x8*)(vbp + 32), acc[dt]);
    }
    __builtin_amdgcn_s_setprio(0);
  }

  // ---- combine the two K-halves of each pair via LDS (reuses plds; 2x1040 fp32 <= 2176) ----
  float* fb = ((float*)&plds[0][0]) + p * 1040;
  __syncthreads();                       // all waves done with their P tiles
  if (half == 1) {                       // donor: keys 512..1023 partials
#pragma unroll
    for (int dt = 0; dt < 4; ++dt)
#pragma unroll
      for (int r = 0; r < 4; ++r)
        fb[(hi * 4 + r) * 64 + dt * 16 + lo] = acc[dt][r];
    if (lo == 0)
#pragma unroll
      for (int r = 0; r < 4; ++r) fb[1024 + hi * 4 + r] = sacc[r];
  }
  __syncthreads();
  if (half == 0) {                       // receiver: add, normalize, store
    const int b = bh >> 3, h = bh & 7;
#pragma unroll
    for (int r = 0; r < 4; ++r) {
      const float zt = sacc[r] + fb[1024 + hi * 4 + r];
      const float inv = 1.0f / zt;
      const int tok = (b << 10) + qs + hi * 4 + r;
#pragma unroll
      for (int dt = 0; dt < 4; ++dt) {
        const float av = acc[dt][r] + fb[(hi * 4 + r) * 64 + dt * 16 + lo];
        aout[(size_t)tok * 512 + h * 64 + dt * 16 + lo] = f2bf(av * inv);
      }
    }
  }
}

extern "C" void kernel_launch(void* const* d_in, const int* in_sizes, int n_in,
                              void* d_out, int out_size, void* d_ws, size_t ws_size,
                              hipStream_t stream) {
  const float* x      = (const float*)d_in[0];
  const float* qkv_w  = (const float*)d_in[1];
  const float* qkv_b  = (const float*)d_in[2];
  const float* proj_w = (const float*)d_in[3];
  const float* proj_b = (const float*)d_in[4];
  float* out = (float*)d_out;
  char* ws = (char*)d_ws;

  unsigned short* xb  = (unsigned short*)(ws);             // 8,388,608 (x bf16; reused as attn_out)
  unsigned short* qwb = (unsigned short*)(ws +  8388608);  // 1,572,864
  unsigned short* pwb = (unsigned short*)(ws +  9961472);  //   524,288
  unsigned short* Qb  = (unsigned short*)(ws + 10485760);  // 8,388,608 [bh][n][d], pre-scaled
  unsigned short* Kb  = (unsigned short*)(ws + 18874368);  // 8,388,608 [bh][n][d]
  unsigned short* VTb = (unsigned short*)(ws + 27262976);  // 8,388,608 [bh][d][n]

  cvt_kernel<<<5120, 256, 0, stream>>>(x, qkv_w, proj_w, xb, qwb, pwb);
  gemm_kernel<0><<<dim3(12, 64), 256, 0, stream>>>(xb, qwb, qkv_b, Qb, Kb, VTb, nullptr);
  attn_kernel<<<2048, 256, 0, stream>>>(Qb, Kb, VTb, xb);
  gemm_kernel<1><<<dim3(4, 64), 256, 0, stream>>>(xb, pwb, proj_b, nullptr, nullptr, nullptr, out);
}